// Round 9
// baseline (624.094 us; speedup 1.0000x reference)
//
#include <hip/hip_runtime.h>
#include <hip/hip_bf16.h>
#include <math.h>

#define NTOK 4096
#define DD 1024
#define FF 4096
#define NE 8
#define KSEL 2
#define BK 64
#define PADR 256
#define MT 40          // row tiles (256 each) capacity = 10240
#define KP2 4          // gemm2 split-K

typedef __attribute__((ext_vector_type(8))) short short8_t;
typedef __attribute__((ext_vector_type(4))) float f32x4;

__device__ __forceinline__ unsigned short f2bf(float f){
  unsigned u = __float_as_uint(f);
  return (unsigned short)((u + 0x7fffu + ((u >> 16) & 1u)) >> 16);
}

__device__ __forceinline__ int xcd_swz(int lin, int nwg){
  int q = nwg >> 3, r = nwg & 7;
  int xcd = lin & 7, idx = lin >> 3;
  return (xcd < r ? xcd * (q + 1) : r * (q + 1) + (xcd - r) * q) + idx;
}

#define GLOAD_LDS(g, l) \
  __builtin_amdgcn_global_load_lds((const __attribute__((address_space(1))) void*)(g), \
                                   (__attribute__((address_space(3))) void*)(l), 16, 0, 0)
#define VMCNT0 asm volatile("s_waitcnt vmcnt(0)" ::: "memory")
#define RAWBAR __builtin_amdgcn_s_barrier()
#define SCHEDB __builtin_amdgcn_sched_barrier(0)
#define PRIO1 __builtin_amdgcn_s_setprio(1)
#define PRIO0 __builtin_amdgcn_s_setprio(0)

// ---------------- prep: convert x -> bf16, gating top2 ----------------

__global__ void k_prep(const float* __restrict__ x, const float* __restrict__ wg,
                       short* __restrict__ xb, int* __restrict__ topk_idx,
                       float* __restrict__ topk_gate, int* __restrict__ counts){
  int wid = threadIdx.x >> 6, lane = threadIdx.x & 63;
  int t = blockIdx.x * 4 + wid;
  const float* xr = x + (size_t)t * DD;
  short* xbr = xb + (size_t)t * DD;
  double acc[NE];
#pragma unroll
  for (int e = 0; e < NE; ++e) acc[e] = 0.0;
#pragma unroll
  for (int p = 0; p < 4; ++p){
    int d = p * 256 + lane * 4;
    float4 v = *(const float4*)(xr + d);
    short4 o;
    o.x = (short)f2bf(v.x); o.y = (short)f2bf(v.y);
    o.z = (short)f2bf(v.z); o.w = (short)f2bf(v.w);
    *(short4*)(xbr + d) = o;
    const float* w0 = wg + (size_t)d * NE;
    float vv[4] = {v.x, v.y, v.z, v.w};
#pragma unroll
    for (int j = 0; j < 4; ++j){
      double xv = (double)vv[j];
#pragma unroll
      for (int e = 0; e < NE; ++e) acc[e] += xv * (double)w0[j * NE + e];
    }
  }
#pragma unroll
  for (int e = 0; e < NE; ++e){
#pragma unroll
    for (int s = 32; s; s >>= 1) acc[e] += __shfl_xor(acc[e], s, 64);
  }
  if (lane == 0){
    int i0 = 0; double v0 = acc[0];
#pragma unroll
    for (int e = 1; e < NE; ++e) if (acc[e] > v0){ v0 = acc[e]; i0 = e; }
    int i1 = -1; double v1 = -1e300;
#pragma unroll
    for (int e = 0; e < NE; ++e) if (e != i0 && acc[e] > v1){ v1 = acc[e]; i1 = e; }
    double g0 = 1.0 / (1.0 + exp(v1 - v0));
    topk_idx[2 * t] = i0; topk_idx[2 * t + 1] = i1;
    topk_gate[2 * t] = (float)g0; topk_gate[2 * t + 1] = (float)(1.0 - g0);
    atomicAdd(&counts[i0], 1);
    atomicAdd(&counts[i1], 1);
  }
}

// ---------------- weight transpose+convert (one matrix set per launch) ----------------

__global__ void k_transpose(const float* __restrict__ W, short* __restrict__ Wt, int isW2){
  __shared__ short T[64][132];
  int id = blockIdx.x;
  int e = id >> 9;
  int tr = id & 511;
  int R, C, c0, r0;
  if (!isW2){ R = DD; C = FF; c0 = (tr & 63) * 64; r0 = (tr >> 6) * 128; }
  else      { R = FF; C = DD; c0 = (tr & 15) * 64; r0 = (tr >> 4) * 128; }
  const float* in = W + (size_t)e * R * C;
  short* out = Wt + (size_t)e * R * C;
  int t = threadIdx.x;
  int rr = t >> 4, c4 = (t & 15) * 4;
#pragma unroll
  for (int p = 0; p < 8; ++p){
    int row = p * 16 + rr;
    float4 v = *(const float4*)(in + (size_t)(r0 + row) * C + c0 + c4);
    T[c4 + 0][row] = (short)f2bf(v.x);
    T[c4 + 1][row] = (short)f2bf(v.y);
    T[c4 + 2][row] = (short)f2bf(v.z);
    T[c4 + 3][row] = (short)f2bf(v.w);
  }
  __syncthreads();
  int c8 = (t & 15) * 8;
#pragma unroll
  for (int q = 0; q < 4; ++q){
    int orow = q * 16 + rr;
    short4 lo = *(const short4*)&T[orow][c8];
    short4 hi = *(const short4*)&T[orow][c8 + 4];
    short8_t w;
    w[0] = lo.x; w[1] = lo.y; w[2] = lo.z; w[3] = lo.w;
    w[4] = hi.x; w[5] = hi.y; w[6] = hi.z; w[7] = hi.w;
    *(short8_t*)(out + (size_t)(c0 + orow) * R + r0 + c8) = w;
  }
}

// ---------------- routing (single block): pad-256 scan + slot assign ----------------

__global__ void k_route_all(const int* __restrict__ counts, const int* __restrict__ topk_idx,
                            const float* __restrict__ topk_gate, int* __restrict__ poff_g,
                            int* __restrict__ row_token, float* __restrict__ row_gate){
  __shared__ int poff[NE + 1], cur[NE], rends[NE];
  if (threadIdx.x == 0){
    int off = 0;
    for (int e = 0; e < NE; ++e){
      poff[e] = off; cur[e] = off; rends[e] = off + counts[e];
      off += (counts[e] + PADR - 1) & ~(PADR - 1);
    }
    poff[NE] = off;
    for (int e = 0; e <= NE; ++e) poff_g[e] = poff[e];
  }
  __syncthreads();
  for (int t = threadIdx.x; t < NTOK; t += 256){
#pragma unroll
    for (int k = 0; k < KSEL; ++k){
      int e = topk_idx[2 * t + k];
      int slot = atomicAdd(&cur[e], 1);
      row_token[slot] = t;
      row_gate[slot] = topk_gate[2 * t + k];
    }
  }
  __syncthreads();
#pragma unroll
  for (int e = 0; e < NE; ++e)
    for (int s = rends[e] + (int)threadIdx.x; s < poff[e + 1]; s += 256){
      row_token[s] = 0; row_gate[s] = 0.f;
    }
}

// ---------------- GEMM1: h = gelu(Xgather @ W1[e] + b1[e]) ----------------
// 256x256, 8 waves (4M x 2N), BK=64, front-loaded staging, once-per-tile drain.

__launch_bounds__(512, 2)
__global__ void k_gemm1(const short* __restrict__ xb, const short* __restrict__ w1t,
                        const float* __restrict__ b1, short* __restrict__ h,
                        const int* __restrict__ row_token, const int* __restrict__ poff){
  __shared__ short As[2][2][8192];   // [buf][Mhalf][128*64]
  __shared__ short Bs[2][2][8192];   // [buf][Nhalf][128*64]
  int lin = xcd_swz(blockIdx.x, MT * (FF / 256));   // 640
  int chunk = lin / 80, idx = lin % 80;
  int bx = chunk * 5 + idx % 5;      // 5 bx per XCD chunk: A ~2.5MB L2-resident
  int by = idx / 5;                  // by inner: B panel 512KB active
  int row0 = bx * 256;
  if (row0 >= poff[NE]) return;
  int e = 0;
  while (row0 >= poff[e + 1]) ++e;
  int n0 = by * 256;
  int tid = threadIdx.x;
  int wid = tid >> 6, lane = tid & 63;
  int wr = wid >> 1, wc = wid & 1;
  int lrow = lane & 15, lk = lane >> 4;

  const short* a_src[2][2]; const short* b_src[2][2];
  {
    int r = tid >> 3, cd = (tid & 7) ^ (r & 7);
    int r2 = (512 + tid) >> 3, cd2 = ((512 + tid) & 7) ^ (r2 & 7);
#pragma unroll
    for (int h2 = 0; h2 < 2; ++h2){
      int tokA = row_token[row0 + h2 * 128 + r];
      int tokB = row_token[row0 + h2 * 128 + r2];
      a_src[h2][0] = xb + (size_t)tokA * DD + cd * 8;
      a_src[h2][1] = xb + (size_t)tokB * DD + cd2 * 8;
      b_src[h2][0] = w1t + (size_t)e * FF * DD + (size_t)(n0 + h2 * 128 + r) * DD + cd * 8;
      b_src[h2][1] = w1t + (size_t)e * FF * DD + (size_t)(n0 + h2 * 128 + r2) * DD + cd2 * 8;
    }
  }

  f32x4 acc[4][8];
#pragma unroll
  for (int i = 0; i < 4; ++i)
#pragma unroll
    for (int j = 0; j < 8; ++j) acc[i][j] = (f32x4){0.f, 0.f, 0.f, 0.f};

  auto SA = [&](int nb, int k0){
#pragma unroll
    for (int h2 = 0; h2 < 2; ++h2){
      GLOAD_LDS(a_src[h2][0] + k0, &As[nb][h2][0] + tid * 8);
      GLOAD_LDS(a_src[h2][1] + k0, &As[nb][h2][0] + 4096 + tid * 8);
    }
  };
  auto SB = [&](int nb, int k0){
#pragma unroll
    for (int h2 = 0; h2 < 2; ++h2){
      GLOAD_LDS(b_src[h2][0] + k0, &Bs[nb][h2][0] + tid * 8);
      GLOAD_LDS(b_src[h2][1] + k0, &Bs[nb][h2][0] + 4096 + tid * 8);
    }
  };
  auto rdA = [&](const short* Ab, int kk, short8_t* av){
#pragma unroll
    for (int m = 0; m < 4; ++m){
      int r = (wr & 1) * 64 + m * 16 + lrow;
      av[m] = *(const short8_t*)(Ab + r * 64 + (((kk * 4 + lk) ^ (r & 7)) << 3));
    }
  };
  auto rdB = [&](const short* Bb, int kk, short8_t* bv){
#pragma unroll
    for (int n = 0; n < 4; ++n){
      int r = wc * 64 + n * 16 + lrow;
      bv[n] = *(const short8_t*)(Bb + r * 64 + (((kk * 4 + lk) ^ (r & 7)) << 3));
    }
  };
  auto MF = [&](int nh, short8_t* av, short8_t* bv){
#pragma unroll
    for (int m = 0; m < 4; ++m)
#pragma unroll
      for (int n = 0; n < 4; ++n)
        acc[m][nh * 4 + n] = __builtin_amdgcn_mfma_f32_16x16x32_bf16(av[m], bv[n], acc[m][nh * 4 + n], 0, 0, 0);
  };

  // prologue: tile0 -> buf0
  SA(0, 0); SB(0, 0);
  VMCNT0; RAWBAR; SCHEDB;

  const int NKT = DD / BK;   // 16
#pragma unroll 1
  for (int g = 0; g < NKT; ++g){
    int b = g & 1, nb = b ^ 1;
    int k1 = (g + 1) * BK;
    bool more = (g + 1 < NKT);
    const short* Ab = &As[b][wr >> 1][0];
    short8_t av[4], bv[4];
    // ph0
    if (more) SA(nb, k1);
    rdA(Ab, 0, av); rdB(&Bs[b][0][0], 0, bv);
    RAWBAR; SCHEDB; PRIO1; MF(0, av, bv); PRIO0; RAWBAR; SCHEDB;
    // ph1
    if (more) SB(nb, k1);
    rdB(&Bs[b][1][0], 0, bv);
    RAWBAR; SCHEDB; PRIO1; MF(1, av, bv); PRIO0; RAWBAR; SCHEDB;
    // ph2
    rdA(Ab, 1, av); rdB(&Bs[b][0][0], 1, bv);
    RAWBAR; SCHEDB; PRIO1; MF(0, av, bv); PRIO0; RAWBAR; SCHEDB;
    // ph3
    rdB(&Bs[b][1][0], 1, bv);
    RAWBAR; SCHEDB; PRIO1; MF(1, av, bv); PRIO0;
    if (more) VMCNT0;
    RAWBAR; SCHEDB;
  }

  // epilogue: gelu + bias; wave-private 16x128 LDS bounce (only the wave's own
  // columns: nh*128 + wc*64 + 0..63 for nh=0,1); 16B contiguous stores.
  const float* b1e = b1 + (size_t)e * FF;
  float bias8[8];
#pragma unroll
  for (int nh = 0; nh < 2; ++nh)
#pragma unroll
    for (int n = 0; n < 4; ++n)
      bias8[nh * 4 + n] = b1e[n0 + nh * 128 + wc * 64 + n * 16 + lrow];
  short* E = &As[0][0][0] + wid * 2048;   // 16 rows x 128 cols bf16 per wave
#pragma unroll 1
  for (int m = 0; m < 4; ++m){
#pragma unroll
    for (int nh = 0; nh < 2; ++nh)
#pragma unroll
      for (int n = 0; n < 4; ++n)
#pragma unroll
        for (int j = 0; j < 4; ++j){
          float v = acc[m][nh * 4 + n][j] + bias8[nh * 4 + n];
          float u = 0.7978845608028654f * (v + 0.044715f * v * v * v);
          float gl = v / (1.0f + __expf(-2.0f * u));
          E[(lk * 4 + j) * 128 + nh * 64 + n * 16 + lrow] = (short)f2bf(gl);
        }
#pragma unroll
    for (int q = 0; q < 4; ++q){
      int id = q * 64 + lane;          // 0..255
      int r = id >> 4;                 // 0..15 rows
      int c8 = id & 15;                // 16 chunks of 8 shorts
      short8_t w = *(const short8_t*)(E + r * 128 + c8 * 8);
      int row = row0 + wr * 64 + m * 16 + r;
      int col = n0 + (c8 >> 3) * 128 + wc * 64 + (c8 & 7) * 8;
      *(short8_t*)(h + (size_t)row * FF + col) = w;
    }
  }
}

// ---------------- GEMM2 (split-K=4, atomic scatter): out += gate*(H@W2[e] + b2) ----------------

__launch_bounds__(512, 2)
__global__ void k_gemm2(const short* __restrict__ hA, const short* __restrict__ w2t,
                        const float* __restrict__ b2, float* __restrict__ out,
                        const int* __restrict__ row_token, const float* __restrict__ row_gate,
                        const int* __restrict__ poff){
  __shared__ short As[2][2][8192];
  __shared__ short Bs[2][2][8192];
  int lin = xcd_swz(blockIdx.x, MT * (DD / 256) * KP2);   // 640
  int chunk = lin / 80, idx = lin % 80;
  int bx = chunk * 5 + idx % 5;
  int by = (idx / 5) & 3;
  int kz = idx / 20;
  int row0 = bx * 256;
  if (row0 >= poff[NE]) return;
  int e = 0;
  while (row0 >= poff[e + 1]) ++e;
  int n0 = by * 256;
  int kbeg = kz * (FF / KP2);    // 1024
  int tid = threadIdx.x;
  int wid = tid >> 6, lane = tid & 63;
  int wr = wid >> 1, wc = wid & 1;
  int lrow = lane & 15, lk = lane >> 4;

  const short* a_src[2][2]; const short* b_src[2][2];
  {
    int r = tid >> 3, cd = (tid & 7) ^ (r & 7);
    int r2 = (512 + tid) >> 3, cd2 = ((512 + tid) & 7) ^ (r2 & 7);
#pragma unroll
    for (int h2 = 0; h2 < 2; ++h2){
      a_src[h2][0] = hA + (size_t)(row0 + h2 * 128 + r) * FF + kbeg + cd * 8;
      a_src[h2][1] = hA + (size_t)(row0 + h2 * 128 + r2) * FF + kbeg + cd2 * 8;
      b_src[h2][0] = w2t + (size_t)e * DD * FF + (size_t)(n0 + h2 * 128 + r) * FF + kbeg + cd * 8;
      b_src[h2][1] = w2t + (size_t)e * DD * FF + (size_t)(n0 + h2 * 128 + r2) * FF + kbeg + cd2 * 8;
    }
  }

  f32x4 acc[4][8];
#pragma unroll
  for (int i = 0; i < 4; ++i)
#pragma unroll
    for (int j = 0; j < 8; ++j) acc[i][j] = (f32x4){0.f, 0.f, 0.f, 0.f};

  auto SA = [&](int nb, int k0){
#pragma unroll
    for (int h2 = 0; h2 < 2; ++h2){
      GLOAD_LDS(a_src[h2][0] + k0, &As[nb][h2][0] + tid * 8);
      GLOAD_LDS(a_src[h2][1] + k0, &As[nb][h2][0] + 4096 + tid * 8);
    }
  };
  auto SB = [&](int nb, int k0){
#pragma unroll
    for (int h2 = 0; h2 < 2; ++h2){
      GLOAD_LDS(b_src[h2][0] + k0, &Bs[nb][h2][0] + tid * 8);
      GLOAD_LDS(b_src[h2][1] + k0, &Bs[nb][h2][0] + 4096 + tid * 8);
    }
  };
  auto rdA = [&](const short* Ab, int kk, short8_t* av){
#pragma unroll
    for (int m = 0; m < 4; ++m){
      int r = (wr & 1) * 64 + m * 16 + lrow;
      av[m] = *(const short8_t*)(Ab + r * 64 + (((kk * 4 + lk) ^ (r & 7)) << 3));
    }
  };
  auto rdB = [&](const short* Bb, int kk, short8_t* bv){
#pragma unroll
    for (int n = 0; n < 4; ++n){
      int r = wc * 64 + n * 16 + lrow;
      bv[n] = *(const short8_t*)(Bb + r * 64 + (((kk * 4 + lk) ^ (r & 7)) << 3));
    }
  };
  auto MF = [&](int nh, short8_t* av, short8_t* bv){
#pragma unroll
    for (int m = 0; m < 4; ++m)
#pragma unroll
      for (int n = 0; n < 4; ++n)
        acc[m][nh * 4 + n] = __builtin_amdgcn_mfma_f32_16x16x32_bf16(av[m], bv[n], acc[m][nh * 4 + n], 0, 0, 0);
  };

  SA(0, 0); SB(0, 0);
  VMCNT0; RAWBAR; SCHEDB;

  const int NKT = (FF / KP2) / BK;   // 16
#pragma unroll 1
  for (int g = 0; g < NKT; ++g){
    int b = g & 1, nb = b ^ 1;
    int k1 = (g + 1) * BK;
    bool more = (g + 1 < NKT);
    const short* Ab = &As[b][wr >> 1][0];
    short8_t av[4], bv[4];
    if (more) SA(nb, k1);
    rdA(Ab, 0, av); rdB(&Bs[b][0][0], 0, bv);
    RAWBAR; SCHEDB; PRIO1; MF(0, av, bv); PRIO0; RAWBAR; SCHEDB;
    if (more) SB(nb, k1);
    rdB(&Bs[b][1][0], 0, bv);
    RAWBAR; SCHEDB; PRIO1; MF(1, av, bv); PRIO0; RAWBAR; SCHEDB;
    rdA(Ab, 1, av); rdB(&Bs[b][0][0], 1, bv);
    RAWBAR; SCHEDB; PRIO1; MF(0, av, bv); PRIO0; RAWBAR; SCHEDB;
    rdB(&Bs[b][1][0], 1, bv);
    RAWBAR; SCHEDB; PRIO1; MF(1, av, bv); PRIO0;
    if (more) VMCNT0;
    RAWBAR; SCHEDB;
  }

  const float* b2e = b2 + (size_t)e * DD;
  float bias8[8];
#pragma unroll
  for (int nh = 0; nh < 2; ++nh)
#pragma unroll
    for (int n = 0; n < 4; ++n)
      bias8[nh * 4 + n] = (kz == 0) ? b2e[n0 + nh * 128 + wc * 64 + n * 16 + lrow] : 0.0f;
#pragma unroll
  for (int m = 0; m < 4; ++m){
#pragma unroll
    for (int j = 0; j < 4; ++j){
      int row = row0 + wr * 64 + m * 16 + lk * 4 + j;
      float gt = row_gate[row];
      if (gt != 0.f){
        int tok = row_token[row];
        float* orow = out + (size_t)tok * DD;
#pragma unroll
        for (int nh = 0; nh < 2; ++nh)
#pragma unroll
          for (int n = 0; n < 4; ++n){
            int col = n0 + nh * 128 + wc * 64 + n * 16 + lrow;
            atomicAdd(&orow[col], gt * (acc[m][nh * 4 + n][j] + bias8[nh * 4 + n]));
          }
      }
    }
  }
}

// ---------------- launch ----------------

extern "C" void kernel_launch(void* const* d_in, const int* in_sizes, int n_in,
                              void* d_out, int out_size, void* d_ws, size_t ws_size,
                              hipStream_t stream){
  (void)in_sizes; (void)n_in; (void)out_size; (void)ws_size;
  const float* x  = (const float*)d_in[0];
  const float* Wg = (const float*)d_in[1];
  const float* W1 = (const float*)d_in[2];
  const float* b1 = (const float*)d_in[3];
  const float* W2 = (const float*)d_in[4];
  const float* b2 = (const float*)d_in[5];
  float* out = (float*)d_out;
  char* ws = (char*)d_ws;

  int*   counts    = (int*)(ws + 0);
  int*   poff      = (int*)(ws + 64);
  int*   topk_idx  = (int*)(ws + 1024);            // 32768
  float* topk_gate = (float*)(ws + 33792);         // 32768 -> 66560
  int*   row_token = (int*)(ws + 66560);           // 40960 -> 107520
  float* row_gate  = (float*)(ws + 107520);        // 40960 -> 148480
  short* xb        = (short*)(ws + 148480);        // 8 MB  -> 8537088
  short* w1t       = (short*)(ws + 8537088);       // 64 MB -> 75645952
  short* h         = (short*)(ws + 75645952);      // 80 MB -> 159532032
  // w2t reuses [xb, w1t) region — both dead once gemm1 finishes (stream-serial)
  short* w2t       = (short*)(ws + 148480);

  hipMemsetAsync(counts, 0, 64, stream);
  hipMemsetAsync(out, 0, (size_t)NTOK * DD * sizeof(float), stream);

  k_prep<<<dim3(NTOK / 4), 256, 0, stream>>>(x, Wg, xb, topk_idx, topk_gate, counts);
  k_transpose<<<dim3(4096), 256, 0, stream>>>(W1, w1t, 0);
  k_route_all<<<dim3(1), 256, 0, stream>>>(counts, topk_idx, topk_gate, poff,
                                           row_token, row_gate);
  k_gemm1<<<dim3(MT * (FF / 256)), 512, 0, stream>>>(xb, w1t, b1, h, row_token, poff);
  k_transpose<<<dim3(4096), 256, 0, stream>>>(W2, w2t, 1);
  k_gemm2<<<dim3(MT * (DD / 256) * KP2), 512, 0, stream>>>(h, w2t, b2, out,
                                                           row_token, row_gate, poff);
}